// Round 9
// baseline (537.113 us; speedup 1.0000x reference)
//
#include <hip/hip_runtime.h>

#define DD 48
#define TT 512
#define RS 100   // bp row stride: A cols 0..47, B cols 48..95, dump 96..99
#define PF 4     // emit ring depth == inner unroll (static slots)

__device__ __forceinline__ float readlane_f(float v, int lane) {
  return __int_as_float(__builtin_amdgcn_readlane(__float_as_int(v), lane));
}

// Value: max3 tree (depth 4, VGPR-only). Index: pairwise first-index-wins tree
// off the value path. Ties: move right only on strict (r > l).
__device__ __forceinline__ void tree_argmax48(const float* s, float& best, int& idx) {
  float m1[16];
#pragma unroll
  for (int k = 0; k < 16; ++k)
    m1[k] = fmaxf(fmaxf(s[3 * k], s[3 * k + 1]), s[3 * k + 2]);
  float m2[6];
#pragma unroll
  for (int k = 0; k < 5; ++k)
    m2[k] = fmaxf(fmaxf(m1[3 * k], m1[3 * k + 1]), m1[3 * k + 2]);
  m2[5] = m1[15];
  best = fmaxf(fmaxf(fmaxf(m2[0], m2[1]), m2[2]),
               fmaxf(fmaxf(m2[3], m2[4]), m2[5]));

  int x1[24]; float v1[24];
#pragma unroll
  for (int k = 0; k < 24; ++k) {
    float l = s[2 * k], r = s[2 * k + 1];
    v1[k] = fmaxf(l, r);
    x1[k] = (r > l) ? 2 * k + 1 : 2 * k;
  }
  int x2[12]; float v2[12];
#pragma unroll
  for (int k = 0; k < 12; ++k) {
    float l = v1[2 * k], r = v1[2 * k + 1];
    v2[k] = fmaxf(l, r);
    x2[k] = (r > l) ? x1[2 * k + 1] : x1[2 * k];
  }
  int x3[6]; float v3[6];
#pragma unroll
  for (int k = 0; k < 6; ++k) {
    float l = v2[2 * k], r = v2[2 * k + 1];
    v3[k] = fmaxf(l, r);
    x3[k] = (r > l) ? x2[2 * k + 1] : x2[2 * k];
  }
  int x4[3]; float v4[3];
#pragma unroll
  for (int k = 0; k < 3; ++k) {
    float l = v3[2 * k], r = v3[2 * k + 1];
    v4[k] = fmaxf(l, r);
    x4[k] = (r > l) ? x3[2 * k + 1] : x3[2 * k];
  }
  float vm = fmaxf(v4[0], v4[1]);
  int xm = (v4[1] > v4[0]) ? x4[1] : x4[0];
  idx = (v4[2] > vm) ? x4[2] : xm;
}

__global__ __launch_bounds__(64, 1) void crf_viterbi(const float* __restrict__ logits,
                                                     const int* __restrict__ lens,
                                                     const float* __restrict__ trans,
                                                     int* __restrict__ out) {
  const int blk = blockIdx.x;
  const int j = threadIdx.x;
  const int jj = j < DD ? j : DD - 1;

  __shared__ unsigned char bp[(TT + PF) * RS]; // ~51.6 KB, rows padded for tail overrun

  float tcol[DD];
#pragma unroll
  for (int i = 0; i < DD; ++i) tcol[i] = trans[i * DD + jj];

  const float* lgA = logits + (size_t)(2 * blk) * TT * DD;
  const float* lgB = logits + (size_t)(2 * blk + 1) * TT * DD;
  const int LA = lens[2 * blk];
  const int LB = lens[2 * blk + 1];
  const int Lmax = LA > LB ? LA : LB;

  float alphaA = lgA[jj];
  float alphaB = lgB[jj];

  const int colA = (j < DD) ? j : 96;      // dump cols for lanes 48..63
  const int colB = (j < DD) ? DD + j : 98;

  // depth-4 emit rings, static slots
  float eA0 = lgA[1 * DD + jj], eA1 = lgA[2 * DD + jj],
        eA2 = lgA[3 * DD + jj], eA3 = lgA[4 * DD + jj];
  float eB0 = lgB[1 * DD + jj], eB1 = lgB[2 * DD + jj],
        eB2 = lgB[3 * DD + jj], eB3 = lgB[4 * DD + jj];

  // one lockstep paired step at time t (uniform); freeze past each L
#define STEP2(EA, EB)                                                       \
  {                                                                         \
    float sA[DD], sB[DD];                                                   \
    _Pragma("unroll")                                                       \
    for (int i = 0; i < DD; ++i) {                                          \
      float aA = readlane_f(alphaA, i);                                     \
      float aB = readlane_f(alphaB, i);                                     \
      sA[i] = aA + tcol[i];                                                 \
      sB[i] = aB + tcol[i];                                                 \
    }                                                                       \
    float bestA; int idxA; tree_argmax48(sA, bestA, idxA);                  \
    float bestB; int idxB; tree_argmax48(sB, bestB, idxB);                  \
    alphaA = (t < LA) ? (bestA + (EA)) : alphaA;                            \
    alphaB = (t < LB) ? (bestB + (EB)) : alphaB;                            \
    bp[t * RS + colA] = (unsigned char)idxA;                                \
    bp[t * RS + colB] = (unsigned char)idxB;                                \
  }

#define RELOAD2(EA, EB)                                \
  {                                                    \
    int r = t + PF; r = r > TT - 1 ? TT - 1 : r;       \
    EA = lgA[r * DD + jj];                             \
    EB = lgB[r * DD + jj];                             \
  }

  for (int tb = 1; tb < Lmax; tb += PF) {
    { const int t = tb + 0; STEP2(eA0, eB0); RELOAD2(eA0, eB0); }
    { const int t = tb + 1; STEP2(eA1, eB1); RELOAD2(eA1, eB1); }
    { const int t = tb + 2; STEP2(eA2, eB2); RELOAD2(eA2, eB2); }
    { const int t = tb + 3; STEP2(eA3, eB3); RELOAD2(eA3, eB3); }
  }
#undef STEP2
#undef RELOAD2

  __syncthreads(); // single wave; ordering formality before backtrack

  // final argmax per sequence
  float afA[DD], afB[DD];
#pragma unroll
  for (int i = 0; i < DD; ++i) {
    afA[i] = readlane_f(alphaA, i);
    afB[i] = readlane_f(alphaB, i);
  }
  float bvA; int btagA; tree_argmax48(afA, bvA, btagA);
  float bvB; int btagB; tree_argmax48(afB, bvB, btagB);

  int* obA = out + (size_t)(2 * blk) * TT;
  int* obB = out + (size_t)(2 * blk + 1) * TT;
  if (j == 0) {
    obA[LA - 1] = btagA;
    obB[LB - 1] = btagB;
  }

  // interleaved backtracks: H' = bp_t[H] via one shfl per seq per step
  int HA = j, HB = j;
  for (int tt = Lmax - 1; tt >= 1; --tt) {
    if (tt < LA) {
      int vA = bp[tt * RS + jj];
      HA = __shfl(vA, HA, 64);
      if (j == btagA) obA[tt - 1] = HA;
    }
    if (tt < LB) {
      int vB = bp[tt * RS + DD + jj];
      HB = __shfl(vB, HB, 64);
      if (j == btagB) obB[tt - 1] = HB;
    }
  }

  // zero padded tails
  for (int tt = LA + j; tt < TT; tt += 64) obA[tt] = 0;
  for (int tt = LB + j; tt < TT; tt += 64) obB[tt] = 0;
}

extern "C" void kernel_launch(void* const* d_in, const int* in_sizes, int n_in,
                              void* d_out, int out_size, void* d_ws, size_t ws_size,
                              hipStream_t stream) {
  const float* logits = (const float*)d_in[0];
  const int* lens     = (const int*)d_in[1];
  const float* trans  = (const float*)d_in[2];
  int* out            = (int*)d_out;
  (void)in_sizes; (void)n_in; (void)out_size; (void)d_ws; (void)ws_size;
  crf_viterbi<<<256, 64, 0, stream>>>(logits, lens, trans, out);
}

// Round 10
// 277.061 us; speedup vs baseline: 1.9386x; 1.9386x over previous
//
#include <hip/hip_runtime.h>

#define DD 48
#define TT 512
#define BB 512
#define STRIDE 64  // padded LDS row stride for bp
#define PF 16      // emit ring depth == inner unroll (R3's measured-best)

__device__ __forceinline__ float readlane_f(float v, int lane) {
  return __int_as_float(__builtin_amdgcn_readlane(__float_as_int(v), lane));
}

// Value: pairwise fmax chain (VCC-free). Index: cmp/select off the value path.
// First-index wins ties: move right only on strict (r > l).
__device__ __forceinline__ void tree_argmax48(const float* s, float& best, int& idx) {
  float v1[24]; int x1[24];
#pragma unroll
  for (int k = 0; k < 24; ++k) {
    float l = s[2 * k], r = s[2 * k + 1];
    v1[k] = fmaxf(l, r);
    x1[k] = (r > l) ? 2 * k + 1 : 2 * k;
  }
  float v2[12]; int x2[12];
#pragma unroll
  for (int k = 0; k < 12; ++k) {
    float l = v1[2 * k], r = v1[2 * k + 1];
    v2[k] = fmaxf(l, r);
    x2[k] = (r > l) ? x1[2 * k + 1] : x1[2 * k];
  }
  float v3[6]; int x3[6];
#pragma unroll
  for (int k = 0; k < 6; ++k) {
    float l = v2[2 * k], r = v2[2 * k + 1];
    v3[k] = fmaxf(l, r);
    x3[k] = (r > l) ? x2[2 * k + 1] : x2[2 * k];
  }
  float v4[3]; int x4[3];
#pragma unroll
  for (int k = 0; k < 3; ++k) {
    float l = v3[2 * k], r = v3[2 * k + 1];
    v4[k] = fmaxf(l, r);
    x4[k] = (r > l) ? x3[2 * k + 1] : x3[2 * k];
  }
  float vm = fmaxf(v4[0], v4[1]);
  int xm = (v4[1] > v4[0]) ? x4[1] : x4[0];
  best = fmaxf(vm, v4[2]);
  idx = (v4[2] > vm) ? x4[2] : xm;
}

__global__ __launch_bounds__(64, 1) void crf_viterbi(const float* __restrict__ logits,
                                                     const int* __restrict__ lens,
                                                     const float* __restrict__ trans,
                                                     int* __restrict__ out) {
  const int b = blockIdx.x;
  const int j = threadIdx.x;          // lanes 0..47 are live tags
  const int jj = j < DD ? j : DD - 1; // clamp for safe reads

  __shared__ unsigned char bp[TT * STRIDE]; // 32 KB backpointers

  float tcol[DD];
#pragma unroll
  for (int i = 0; i < DD; ++i) tcol[i] = trans[i * DD + jj];

  const float* lg = logits + (size_t)b * TT * DD;
  const int L = lens[b];

  float alpha = lg[jj]; // alpha0

  // 16-deep emit ring, static slots (rows 1..16 always allocated: TT=512)
  float e0  = lg[ 1 * DD + jj], e1  = lg[ 2 * DD + jj],
        e2  = lg[ 3 * DD + jj], e3  = lg[ 4 * DD + jj],
        e4  = lg[ 5 * DD + jj], e5  = lg[ 6 * DD + jj],
        e6  = lg[ 7 * DD + jj], e7  = lg[ 8 * DD + jj],
        e8  = lg[ 9 * DD + jj], e9  = lg[10 * DD + jj],
        e10 = lg[11 * DD + jj], e11 = lg[12 * DD + jj],
        e12 = lg[13 * DD + jj], e13 = lg[14 * DD + jj],
        e14 = lg[15 * DD + jj], e15 = lg[16 * DD + jj];

  // one step: batched readlanes (hazard distance), sched fence, adds, tree
#define STEP(EV)                                                   \
  {                                                                \
    float a[DD];                                                   \
    _Pragma("unroll")                                              \
    for (int i = 0; i < DD; ++i) a[i] = readlane_f(alpha, i);      \
    __builtin_amdgcn_sched_barrier(0);                             \
    float s[DD];                                                   \
    _Pragma("unroll")                                              \
    for (int i = 0; i < DD; ++i) s[i] = a[i] + tcol[i];            \
    float best; int idx;                                           \
    tree_argmax48(s, best, idx);                                   \
    alpha = best + (EV);                                           \
    bp[t * STRIDE + j] = (unsigned char)idx;                       \
  }

#define RELOAD(ES)                                 \
  {                                                \
    int r = t + PF; r = r > TT - 1 ? TT - 1 : r;   \
    ES = lg[r * DD + jj];                          \
  }

  int t = 1;
  while (t < L) {
    STEP(e0);  RELOAD(e0);  ++t; if (t >= L) break;
    STEP(e1);  RELOAD(e1);  ++t; if (t >= L) break;
    STEP(e2);  RELOAD(e2);  ++t; if (t >= L) break;
    STEP(e3);  RELOAD(e3);  ++t; if (t >= L) break;
    STEP(e4);  RELOAD(e4);  ++t; if (t >= L) break;
    STEP(e5);  RELOAD(e5);  ++t; if (t >= L) break;
    STEP(e6);  RELOAD(e6);  ++t; if (t >= L) break;
    STEP(e7);  RELOAD(e7);  ++t; if (t >= L) break;
    STEP(e8);  RELOAD(e8);  ++t; if (t >= L) break;
    STEP(e9);  RELOAD(e9);  ++t; if (t >= L) break;
    STEP(e10); RELOAD(e10); ++t; if (t >= L) break;
    STEP(e11); RELOAD(e11); ++t; if (t >= L) break;
    STEP(e12); RELOAD(e12); ++t; if (t >= L) break;
    STEP(e13); RELOAD(e13); ++t; if (t >= L) break;
    STEP(e14); RELOAD(e14); ++t; if (t >= L) break;
    STEP(e15); RELOAD(e15); ++t;
  }
#undef STEP
#undef RELOAD

  __syncthreads(); // single wave; ordering formality before backtrack

  // last_tag = argmax_j alpha (uniform on all lanes)
  float af[DD];
#pragma unroll
  for (int i = 0; i < DD; ++i) af[i] = readlane_f(alpha, i);
  float bv; int btag;
  tree_argmax48(af, bv, btag);

  int* ob = out + (size_t)b * TT;
  if (j == 0) ob[L - 1] = btag;

  // Backtrack by function composition: H[j] = tag at time t given final tag j.
  int H = j;
  for (int tt = L - 1; tt >= 1; --tt) {
    int v = bp[tt * STRIDE + jj]; // addr independent of H -> pipelined
    H = __shfl(v, H, 64);         // H' = bp_t[H]
    if (j == btag) ob[tt - 1] = H;
  }

  // zero the padded tail t >= L
  for (int tt = L + j; tt < TT; tt += 64) ob[tt] = 0;
}

extern "C" void kernel_launch(void* const* d_in, const int* in_sizes, int n_in,
                              void* d_out, int out_size, void* d_ws, size_t ws_size,
                              hipStream_t stream) {
  const float* logits = (const float*)d_in[0];
  const int* lens     = (const int*)d_in[1];
  const float* trans  = (const float*)d_in[2];
  int* out            = (int*)d_out;
  (void)in_sizes; (void)n_in; (void)out_size; (void)d_ws; (void)ws_size;
  crf_viterbi<<<BB, 64, 0, stream>>>(logits, lens, trans, out);
}